// Round 1
// baseline (195.689 us; speedup 1.0000x reference)
//
#include <hip/hip_runtime.h>

#define NNODES 100000
#define EDGES  262144

typedef __attribute__((ext_vector_type(8))) short short8v;
typedef __attribute__((ext_vector_type(8))) unsigned short ushort8v;
typedef __attribute__((ext_vector_type(4))) unsigned short ushort4v;
typedef __attribute__((ext_vector_type(4))) float f32x4;

__device__ __forceinline__ unsigned short f2bf(float f) {
  unsigned u = __builtin_bit_cast(unsigned, f);
  u += 0x7fffu + ((u >> 16) & 1u);
  return (unsigned short)(u >> 16);
}
__device__ __forceinline__ float bf2f(unsigned short u) {
  return __builtin_bit_cast(float, (unsigned)u << 16);
}

// ---------------------------------------------------------------------------
// Kernel 0: repack W1 (fp32 [256][512]) -> Wc (bf16 [512][256], k-major).
// Row j<256  = src-projection row j  (input cols 0:128 then 256:384)
// Row j>=256 = dst-projection row j-256 (input cols 128:256 then 384:512)
// ---------------------------------------------------------------------------
__global__ __launch_bounds__(256) void prep_wc(const float* __restrict__ W1,
                                               unsigned short* __restrict__ Wc) {
  int idx = blockIdx.x * 256 + threadIdx.x;   // 0 .. 512*256-1
  int j = idx >> 8;
  int k = idx & 255;
  int jj = j & 255;
  int kk = (k < 128) ? k : (k + 128);
  if (j >= 256) kk += 128;
  Wc[idx] = f2bf(W1[jj * 512 + kk]);
}

// ---------------------------------------------------------------------------
// Kernel 1: P[n][0:256] = [emb[n],mem[n]] @ Wc[0:256]^T + b1   (src half)
//           P[n][256:512] = [emb[n],mem[n]] @ Wc[256:512]^T     (dst half)
// MFMA bf16 16x16x32.  Block = 256 thr (4 waves), tile = 32 rows x 512 cols.
// Wave w covers cols [w*128, w*128+128): acc[2 row-tiles][8 col-tiles].
// ---------------------------------------------------------------------------
__global__ __launch_bounds__(256) void gemm_proj(const float* __restrict__ ne,
                                                 const float* __restrict__ mem,
                                                 const unsigned short* __restrict__ Wc,
                                                 const float* __restrict__ b1,
                                                 unsigned short* __restrict__ P) {
  __shared__ __align__(16) unsigned short As[32][264];  // pad 264: uniform banks for b128 reads
  const int tid  = threadIdx.x;
  const int tile = blockIdx.x;          // 3125 tiles of 32 rows

  // stage A = [emb | mem] rows, cvt fp32->bf16.  2048 float4 loads / 256 thr.
#pragma unroll
  for (int i = 0; i < 8; ++i) {
    int q   = tid + i * 256;            // 0..2047
    int row = q >> 6;                   // 0..31
    int k0  = (q & 63) * 4;             // 0..252
    int node = tile * 32 + row;
    const float* sp = (k0 < 128) ? (ne + (size_t)node * 128 + k0)
                                 : (mem + (size_t)node * 128 + (k0 - 128));
    float4 v = *(const float4*)sp;
    ushort4v o;
    o[0] = f2bf(v.x); o[1] = f2bf(v.y); o[2] = f2bf(v.z); o[3] = f2bf(v.w);
    *(ushort4v*)&As[row][k0] = o;
  }
  __syncthreads();

  const int wid  = tid >> 6;
  const int lane = tid & 63;
  const int cb   = wid * 128;
  const int lr   = lane & 15;
  const int kq   = (lane >> 4) * 8;

  f32x4 acc[2][8] = {};
#pragma unroll
  for (int ks = 0; ks < 8; ++ks) {
    const int kk = ks * 32 + kq;
    ushort8v a0 = *(const ushort8v*)&As[lr][kk];
    ushort8v a1 = *(const ushort8v*)&As[lr + 16][kk];
#pragma unroll
    for (int ct = 0; ct < 8; ++ct) {
      int col = cb + ct * 16 + lr;
      ushort8v bf = *(const ushort8v*)(Wc + (size_t)col * 256 + kk);
      acc[0][ct] = __builtin_amdgcn_mfma_f32_16x16x32_bf16((short8v)a0, (short8v)bf, acc[0][ct], 0, 0, 0);
      acc[1][ct] = __builtin_amdgcn_mfma_f32_16x16x32_bf16((short8v)a1, (short8v)bf, acc[1][ct], 0, 0, 0);
    }
  }

  // epilogue: C layout col=lane&15, row=(lane>>4)*4+reg  [m89]
#pragma unroll
  for (int rt = 0; rt < 2; ++rt) {
#pragma unroll
    for (int ct = 0; ct < 8; ++ct) {
      int col = cb + ct * 16 + lr;
      float badd = (col < 256) ? b1[col] : 0.0f;
#pragma unroll
      for (int r = 0; r < 4; ++r) {
        int row  = rt * 16 + (lane >> 4) * 4 + r;
        int node = tile * 32 + row;
        P[(size_t)node * 512 + col] = f2bf(acc[rt][ct][r] + badd);
      }
    }
  }
}

// ---------------------------------------------------------------------------
// Kernel 2: per-edge score.  1 wave per edge.
// out[e] = relu(P[src][0:256] + P[dst][256:512]) . W2 + b2
// ---------------------------------------------------------------------------
__global__ __launch_bounds__(256) void edge_score(const int* __restrict__ src,
                                                  const int* __restrict__ dst,
                                                  const unsigned short* __restrict__ P,
                                                  const float* __restrict__ W2,
                                                  const float* __restrict__ b2,
                                                  float* __restrict__ out) {
  const int wid  = threadIdx.x >> 6;
  const int lane = threadIdx.x & 63;
  const int e    = blockIdx.x * 4 + wid;

  float4 w2v = *(const float4*)(W2 + lane * 4);
  const int s = src[e];
  const int d = dst[e];

  ushort4v a = *(const ushort4v*)(P + (size_t)s * 512 + lane * 4);
  ushort4v b = *(const ushort4v*)(P + (size_t)d * 512 + 256 + lane * 4);

  float h0 = bf2f(a[0]) + bf2f(b[0]); h0 = h0 > 0.f ? h0 : 0.f;
  float h1 = bf2f(a[1]) + bf2f(b[1]); h1 = h1 > 0.f ? h1 : 0.f;
  float h2 = bf2f(a[2]) + bf2f(b[2]); h2 = h2 > 0.f ? h2 : 0.f;
  float h3 = bf2f(a[3]) + bf2f(b[3]); h3 = h3 > 0.f ? h3 : 0.f;
  float partial = h0 * w2v.x + h1 * w2v.y + h2 * w2v.z + h3 * w2v.w;

#pragma unroll
  for (int off = 32; off; off >>= 1) partial += __shfl_xor(partial, off, 64);

  if (lane == 0) out[e] = partial + b2[0];
}

// ---------------------------------------------------------------------------
// Fallback (only if ws_size too small): direct per-edge MLP, 8 edges / block.
// ---------------------------------------------------------------------------
__global__ __launch_bounds__(256) void fallback_edge(const int* __restrict__ src,
                                                     const int* __restrict__ dst,
                                                     const float* __restrict__ ne,
                                                     const float* __restrict__ mem,
                                                     const float* __restrict__ W1,
                                                     const float* __restrict__ b1,
                                                     const float* __restrict__ W2,
                                                     const float* __restrict__ b2,
                                                     float* __restrict__ out) {
  __shared__ float hs[8][512];
  __shared__ float red[8][4];
  const int tid = threadIdx.x;
  const int e0  = blockIdx.x * 8;

  for (int idx = tid; idx < 8 * 512; idx += 256) {
    int e8 = idx >> 9, k = idx & 511;
    int e = e0 + e8;
    int s = src[e], d = dst[e];
    float v;
    if (k < 128)      v = ne[(size_t)s * 128 + k];
    else if (k < 256) v = ne[(size_t)d * 128 + k - 128];
    else if (k < 384) v = mem[(size_t)s * 128 + k - 256];
    else              v = mem[(size_t)d * 128 + k - 384];
    hs[e8][k] = v;
  }
  __syncthreads();

  const int j = tid;
  float acc[8] = {0, 0, 0, 0, 0, 0, 0, 0};
  const float* w1r = W1 + (size_t)j * 512;
  for (int k = 0; k < 512; k += 4) {
    float4 w = *(const float4*)(w1r + k);
#pragma unroll
    for (int e8 = 0; e8 < 8; ++e8)
      acc[e8] += hs[e8][k] * w.x + hs[e8][k + 1] * w.y + hs[e8][k + 2] * w.z + hs[e8][k + 3] * w.w;
  }
  const float bj = b1[j], wj = W2[j];
#pragma unroll
  for (int e8 = 0; e8 < 8; ++e8) {
    float h = acc[e8] + bj;
    h = h > 0.f ? h : 0.f;
    acc[e8] = h * wj;
  }
  const int lane = tid & 63, wid = tid >> 6;
#pragma unroll
  for (int e8 = 0; e8 < 8; ++e8) {
    float p = acc[e8];
#pragma unroll
    for (int off = 32; off; off >>= 1) p += __shfl_xor(p, off, 64);
    if (lane == 0) red[e8][wid] = p;
  }
  __syncthreads();
  if (tid < 8) out[e0 + tid] = red[tid][0] + red[tid][1] + red[tid][2] + red[tid][3] + b2[0];
}

// ---------------------------------------------------------------------------
extern "C" void kernel_launch(void* const* d_in, const int* in_sizes, int n_in,
                              void* d_out, int out_size, void* d_ws, size_t ws_size,
                              hipStream_t stream) {
  const int*   src      = (const int*)d_in[0];
  const int*   dst      = (const int*)d_in[1];
  const float* node_emb = (const float*)d_in[4];
  const float* memv     = (const float*)d_in[5];
  const float* W1       = (const float*)d_in[10];
  const float* b1       = (const float*)d_in[11];
  const float* W2       = (const float*)d_in[12];
  const float* b2       = (const float*)d_in[13];
  float*       out      = (float*)d_out;

  const size_t P_BYTES  = (size_t)NNODES * 512 * 2;   // 102,400,000
  const size_t WC_BYTES = (size_t)512 * 256 * 2;      //     262,144

  if (ws_size >= P_BYTES + WC_BYTES) {
    unsigned short* P  = (unsigned short*)d_ws;
    unsigned short* Wc = (unsigned short*)((char*)d_ws + P_BYTES);
    prep_wc<<<512, 256, 0, stream>>>(W1, Wc);
    gemm_proj<<<NNODES / 32, 256, 0, stream>>>(node_emb, memv, Wc, b1, P);
    edge_score<<<EDGES / 4, 256, 0, stream>>>(src, dst, P, W2, b2, out);
  } else {
    fallback_edge<<<EDGES / 8, 256, 0, stream>>>(src, dst, node_emb, memv, W1, b1, W2, b2, out);
  }
}

// Round 2
// 101.650 us; speedup vs baseline: 1.9251x; 1.9251x over previous
//
#include <hip/hip_runtime.h>

#define NNODES 100000
#define EDGES  262144
#define NTILES 3125          // NNODES / 32
#define GEMM_BLOCKS 256

typedef __attribute__((ext_vector_type(8))) short short8v;
typedef __attribute__((ext_vector_type(8))) unsigned short ushort8v;
typedef __attribute__((ext_vector_type(4))) unsigned short ushort4v;
typedef __attribute__((ext_vector_type(4))) float f32x4;

__device__ __forceinline__ unsigned short f2bf(float f) {
  unsigned u = __builtin_bit_cast(unsigned, f);
  u += 0x7fffu + ((u >> 16) & 1u);
  return (unsigned short)(u >> 16);
}
__device__ __forceinline__ float bf2f(unsigned short u) {
  return __builtin_bit_cast(float, (unsigned)u << 16);
}

// ---------------------------------------------------------------------------
// Kernel 0: repack W1 (fp32 [256][512]) -> Wc (bf16 [512][256], k-major).
// Row j<256  = src-projection row j  (input cols 0:128 then 256:384)
// Row j>=256 = dst-projection row j-256 (input cols 128:256 then 384:512)
// ---------------------------------------------------------------------------
__global__ __launch_bounds__(256) void prep_wc(const float* __restrict__ W1,
                                               unsigned short* __restrict__ Wc) {
  int idx = blockIdx.x * 256 + threadIdx.x;   // 0 .. 512*256-1
  int j = idx >> 8;
  int k = idx & 255;
  int jj = j & 255;
  int kk = (k < 128) ? k : (k + 128);
  if (j >= 256) kk += 128;
  Wc[idx] = f2bf(W1[jj * 512 + kk]);
}

// ---------------------------------------------------------------------------
// Kernel 1: persistent-B GEMM.  512 thr = 8 waves; wave w -> cols [w*64,w*64+64).
// B panel (8 ks x 4 ct ushort8v = 128 VGPR) loaded ONCE per block from Wc.
// Each block loops over row-tiles (32 rows) stride-GEMM_BLOCKS with
// double-buffered LDS A-tile and async-split staging (load-early/write-late).
// ---------------------------------------------------------------------------
__global__ __launch_bounds__(512, 2) void gemm_proj2(const float* __restrict__ ne,
                                                     const float* __restrict__ mem,
                                                     const unsigned short* __restrict__ Wc,
                                                     const float* __restrict__ b1,
                                                     unsigned short* __restrict__ P) {
  __shared__ __align__(16) unsigned short As[2][32][264];  // 2 x 16.9 KB, pad->264
  const int tid  = threadIdx.x;
  const int bid  = blockIdx.x;
  const int wid  = tid >> 6;          // 0..7
  const int lane = tid & 63;
  const int lr   = lane & 15;
  const int kq   = (lane >> 4) * 8;   // 0,8,16,24
  const int cb   = wid * 64;

  // ---- B panel into registers (once) ----
  ushort8v bfrag[8][4];
#pragma unroll
  for (int ks = 0; ks < 8; ++ks)
#pragma unroll
    for (int ct = 0; ct < 4; ++ct)
      bfrag[ks][ct] = *(const ushort8v*)(Wc + (size_t)(cb + ct * 16 + lr) * 256 + ks * 32 + kq);

  // ---- bias per lane-col (src half only) ----
  float badd[4];
#pragma unroll
  for (int ct = 0; ct < 4; ++ct)
    badd[ct] = (cb < 256) ? b1[cb + ct * 16 + lr] : 0.0f;

  const int nt = (NTILES - bid + GEMM_BLOCKS - 1) / GEMM_BLOCKS;  // 12 or 13

  // ---- stage tile 0 ----
  float4 g[4];
#pragma unroll
  for (int i = 0; i < 4; ++i) {
    int q = tid + i * 512;            // 0..2047 float4-chunks
    int row = q >> 6;
    int k0  = (q & 63) * 4;           // 0..252
    int node = bid * 32 + row;
    g[i] = *(const float4*)((k0 < 128) ? ne + (size_t)node * 128 + k0
                                       : mem + (size_t)node * 128 + (k0 - 128));
  }
#pragma unroll
  for (int i = 0; i < 4; ++i) {
    int q = tid + i * 512;
    int row = q >> 6;
    int k0  = (q & 63) * 4;
    ushort4v o;
    o[0] = f2bf(g[i].x); o[1] = f2bf(g[i].y); o[2] = f2bf(g[i].z); o[3] = f2bf(g[i].w);
    *(ushort4v*)&As[0][row][k0] = o;
  }
  __syncthreads();

  for (int it = 0; it < nt; ++it) {
    const int tile = bid + it * GEMM_BLOCKS;
    const int buf  = it & 1;

    // issue next tile's global loads EARLY (hide HBM latency under MFMA)
    const bool more = (it + 1 < nt);
    if (more) {
      const int ntile = bid + (it + 1) * GEMM_BLOCKS;
#pragma unroll
      for (int i = 0; i < 4; ++i) {
        int q = tid + i * 512;
        int row = q >> 6;
        int k0  = (q & 63) * 4;
        int node = ntile * 32 + row;
        g[i] = *(const float4*)((k0 < 128) ? ne + (size_t)node * 128 + k0
                                           : mem + (size_t)node * 128 + (k0 - 128));
      }
    }

    // ---- MFMA over K=256: pure ds_read + MFMA ----
    f32x4 acc[2][4] = {};
#pragma unroll
    for (int ks = 0; ks < 8; ++ks) {
      const int kk = ks * 32 + kq;
      ushort8v a0 = *(const ushort8v*)&As[buf][lr][kk];
      ushort8v a1 = *(const ushort8v*)&As[buf][lr + 16][kk];
#pragma unroll
      for (int ct = 0; ct < 4; ++ct) {
        acc[0][ct] = __builtin_amdgcn_mfma_f32_16x16x32_bf16((short8v)a0, (short8v)bfrag[ks][ct], acc[0][ct], 0, 0, 0);
        acc[1][ct] = __builtin_amdgcn_mfma_f32_16x16x32_bf16((short8v)a1, (short8v)bfrag[ks][ct], acc[1][ct], 0, 0, 0);
      }
    }

    // ---- store P tile (fire-and-forget) ----
#pragma unroll
    for (int rt = 0; rt < 2; ++rt)
#pragma unroll
      for (int ct = 0; ct < 4; ++ct)
#pragma unroll
        for (int r = 0; r < 4; ++r) {
          int row  = rt * 16 + (lane >> 4) * 4 + r;
          int node = tile * 32 + row;
          P[(size_t)node * 512 + cb + ct * 16 + lr] = f2bf(acc[rt][ct][r] + badd[ct]);
        }

    // write next tile into the OTHER buffer (current buf still safe: barrier below)
    if (more) {
#pragma unroll
      for (int i = 0; i < 4; ++i) {
        int q = tid + i * 512;
        int row = q >> 6;
        int k0  = (q & 63) * 4;
        ushort4v o;
        o[0] = f2bf(g[i].x); o[1] = f2bf(g[i].y); o[2] = f2bf(g[i].z); o[3] = f2bf(g[i].w);
        *(ushort4v*)&As[buf ^ 1][row][k0] = o;
      }
    }
    __syncthreads();   // one barrier per tile
  }
}

// ---------------------------------------------------------------------------
// Kernel 2: per-edge score.  1 wave per edge.
// out[e] = relu(P[src][0:256] + P[dst][256:512]) . W2 + b2
// ---------------------------------------------------------------------------
__global__ __launch_bounds__(256) void edge_score(const int* __restrict__ src,
                                                  const int* __restrict__ dst,
                                                  const unsigned short* __restrict__ P,
                                                  const float* __restrict__ W2,
                                                  const float* __restrict__ b2,
                                                  float* __restrict__ out) {
  const int wid  = threadIdx.x >> 6;
  const int lane = threadIdx.x & 63;
  const int e    = blockIdx.x * 4 + wid;

  float4 w2v = *(const float4*)(W2 + lane * 4);
  const int s = src[e];
  const int d = dst[e];

  ushort4v a = *(const ushort4v*)(P + (size_t)s * 512 + lane * 4);
  ushort4v b = *(const ushort4v*)(P + (size_t)d * 512 + 256 + lane * 4);

  float h0 = bf2f(a[0]) + bf2f(b[0]); h0 = h0 > 0.f ? h0 : 0.f;
  float h1 = bf2f(a[1]) + bf2f(b[1]); h1 = h1 > 0.f ? h1 : 0.f;
  float h2 = bf2f(a[2]) + bf2f(b[2]); h2 = h2 > 0.f ? h2 : 0.f;
  float h3 = bf2f(a[3]) + bf2f(b[3]); h3 = h3 > 0.f ? h3 : 0.f;
  float partial = h0 * w2v.x + h1 * w2v.y + h2 * w2v.z + h3 * w2v.w;

#pragma unroll
  for (int off = 32; off; off >>= 1) partial += __shfl_xor(partial, off, 64);

  if (lane == 0) out[e] = partial + b2[0];
}

// ---------------------------------------------------------------------------
// Fallback (only if ws_size too small): direct per-edge MLP, 8 edges / block.
// ---------------------------------------------------------------------------
__global__ __launch_bounds__(256) void fallback_edge(const int* __restrict__ src,
                                                     const int* __restrict__ dst,
                                                     const float* __restrict__ ne,
                                                     const float* __restrict__ mem,
                                                     const float* __restrict__ W1,
                                                     const float* __restrict__ b1,
                                                     const float* __restrict__ W2,
                                                     const float* __restrict__ b2,
                                                     float* __restrict__ out) {
  __shared__ float hs[8][512];
  __shared__ float red[8][4];
  const int tid = threadIdx.x;
  const int e0  = blockIdx.x * 8;

  for (int idx = tid; idx < 8 * 512; idx += 256) {
    int e8 = idx >> 9, k = idx & 511;
    int e = e0 + e8;
    int s = src[e], d = dst[e];
    float v;
    if (k < 128)      v = ne[(size_t)s * 128 + k];
    else if (k < 256) v = ne[(size_t)d * 128 + k - 128];
    else if (k < 384) v = mem[(size_t)s * 128 + k - 256];
    else              v = mem[(size_t)d * 128 + k - 384];
    hs[e8][k] = v;
  }
  __syncthreads();

  const int j = tid;
  float acc[8] = {0, 0, 0, 0, 0, 0, 0, 0};
  const float* w1r = W1 + (size_t)j * 512;
  for (int k = 0; k < 512; k += 4) {
    float4 w = *(const float4*)(w1r + k);
#pragma unroll
    for (int e8 = 0; e8 < 8; ++e8)
      acc[e8] += hs[e8][k] * w.x + hs[e8][k + 1] * w.y + hs[e8][k + 2] * w.z + hs[e8][k + 3] * w.w;
  }
  const float bj = b1[j], wj = W2[j];
#pragma unroll
  for (int e8 = 0; e8 < 8; ++e8) {
    float h = acc[e8] + bj;
    h = h > 0.f ? h : 0.f;
    acc[e8] = h * wj;
  }
  const int lane = tid & 63, wid = tid >> 6;
#pragma unroll
  for (int e8 = 0; e8 < 8; ++e8) {
    float p = acc[e8];
#pragma unroll
    for (int off = 32; off; off >>= 1) p += __shfl_xor(p, off, 64);
    if (lane == 0) red[e8][wid] = p;
  }
  __syncthreads();
  if (tid < 8) out[e0 + tid] = red[tid][0] + red[tid][1] + red[tid][2] + red[tid][3] + b2[0];
}

// ---------------------------------------------------------------------------
extern "C" void kernel_launch(void* const* d_in, const int* in_sizes, int n_in,
                              void* d_out, int out_size, void* d_ws, size_t ws_size,
                              hipStream_t stream) {
  const int*   src      = (const int*)d_in[0];
  const int*   dst      = (const int*)d_in[1];
  const float* node_emb = (const float*)d_in[4];
  const float* memv     = (const float*)d_in[5];
  const float* W1       = (const float*)d_in[10];
  const float* b1       = (const float*)d_in[11];
  const float* W2       = (const float*)d_in[12];
  const float* b2       = (const float*)d_in[13];
  float*       out      = (float*)d_out;

  const size_t P_BYTES  = (size_t)NNODES * 512 * 2;   // 102,400,000
  const size_t WC_BYTES = (size_t)512 * 256 * 2;      //     262,144

  if (ws_size >= P_BYTES + WC_BYTES) {
    unsigned short* P  = (unsigned short*)d_ws;
    unsigned short* Wc = (unsigned short*)((char*)d_ws + P_BYTES);
    prep_wc<<<512, 256, 0, stream>>>(W1, Wc);
    gemm_proj2<<<GEMM_BLOCKS, 512, 0, stream>>>(node_emb, memv, Wc, b1, P);
    edge_score<<<EDGES / 4, 256, 0, stream>>>(src, dst, P, W2, b2, out);
  } else {
    fallback_edge<<<EDGES / 8, 256, 0, stream>>>(src, dst, node_emb, memv, W1, b1, W2, b2, out);
  }
}